// Round 13
// baseline (904.491 us; speedup 1.0000x reference)
//
#include <hip/hip_runtime.h>
#include <stdint.h>

typedef unsigned short u16;

#define S_   7
#define B_   4096
#define D_   1024
#define E_   128
#define H_   512
#define V_   200
#define D0_  1152   // D+E
#define K0_  1664   // layer-0 GEMM K: pred 1024 + h0 512 + emb 128
#define KL_  1152   // lin GEMM K: pred 1024 + emb 128
#define KX1  1024   // layer-1 GEMM K: x1 512 + h1 512
#define G4H  2048   // 4H
#define XW   2048   // xcat width: [pred(1024) | h0_a(512) | h0_b(512)]
#define X1W  2048   // x1cat width: [x1_a | x1_b | h1_a | h1_b]

typedef __bf16 bf16x8 __attribute__((ext_vector_type(8)));
typedef float  f32x4  __attribute__((ext_vector_type(4)));
typedef u16    u16x8  __attribute__((ext_vector_type(8)));

__device__ __forceinline__ u16 f2bf(float f) {
  union { float f; uint32_t u; } v; v.f = f;
  uint32_t r = v.u + 0x7fffu + ((v.u >> 16) & 1u);   // RNE
  return (u16)(r >> 16);
}
__device__ __forceinline__ float bf2f(u16 b) {
  union { uint32_t u; float f; } v; v.u = ((uint32_t)b) << 16;
  return v.f;
}
__device__ __forceinline__ float sigmoidf_(float x) { return 1.0f / (1.0f + __expf(-x)); }
__device__ __forceinline__ float tanhf_(float x) {
  float t = __expf(-2.f * fabsf(x));
  return copysignf((1.f - t) / (1.f + t), x);
}

__device__ __forceinline__ void glds16(const u16* g, u16* l) {
  __builtin_amdgcn_global_load_lds(
      (const __attribute__((address_space(1))) uint32_t*)g,
      (__attribute__((address_space(3))) uint32_t*)l, 16, 0, 0);
}

__device__ __forceinline__ void cvt8s(const float* src, u16* dst) {
  const float4* p = (const float4*)src;
  float4 x = p[0], y = p[1];
  u16x8 o;
  o[0]=f2bf(x.x); o[1]=f2bf(x.y); o[2]=f2bf(x.z); o[3]=f2bf(x.w);
  o[4]=f2bf(y.x); o[5]=f2bf(y.y); o[6]=f2bf(y.z); o[7]=f2bf(y.w);
  *(u16x8*)dst = o;
}

// ---------- pack device fns (per-slot pointers) ------------------------------
__device__ __forceinline__ void pk_gates(const float* __restrict__ Wih,
                                         const float* __restrict__ Whh,
                                         u16* __restrict__ dst,
                                         int idx, int stride, int NG, int KK,
                                         int P1, int P2, int KA, int KB) {
  #pragma unroll
  for (int u = 0; u < 4; ++u) {
    int i = idx + u * stride;
    int r = i / NG, kg = i - r * NG;
    int k8 = kg * 8;
    int g = r >> 9, j = r & 511;
    long drow = (j >> 4) * 64 + g * 16 + (j & 15);
    const float* sp = (k8 < P1) ? Wih + (long)r * KA + k8
                    : (k8 < P2) ? Whh + (long)r * KB + (k8 - P1)
                                : Wih + (long)r * KA + P1 + (k8 - P2);
    cvt8s(sp, &dst[drow * KK + k8]);
  }
}
__device__ __forceinline__ void pk_hwn(const float* __restrict__ src,
                                       u16* __restrict__ dst,
                                       int idx, int stride) {
  #pragma unroll
  for (int u = 0; u < 4; ++u) {
    int i = idx + u * stride;
    int r = i / 208, kg = i - r * 208;
    int k8 = kg * 8;
    const float* sp = (k8 < 1024) ? src + (long)r * K0_ + k8
                    : (k8 < 1536) ? src + (long)r * K0_ + 1152 + (k8 - 1024)
                                  : src + (long)r * K0_ + 1024 + (k8 - 1536);
    cvt8s(sp, &dst[(long)r * K0_ + k8]);
  }
}
__device__ __forceinline__ void pk_lin(const float* __restrict__ src,
                                       u16* __restrict__ dst,
                                       int idx, int stride) {
  #pragma unroll
  for (int u = 0; u < 4; ++u) {
    int i = idx + u * stride;
    int r = i / 144, kg = i - r * 144;
    int k8 = kg * 8;
    cvt8s(src + (long)r * KL_ + k8, &dst[(long)r * KL_ + k8]);
  }
}

// ---------- pred pack into xcat[:,0..1024), zeros in both h0 slots -----------
__global__ void pack_predz4(const float* __restrict__ pred, u16* __restrict__ dst) {
  const int NG = XW / 8;   // 256
  const int stride = gridDim.x * 256;
  int idx = blockIdx.x * 256 + threadIdx.x;
  #pragma unroll
  for (int u = 0; u < 4; ++u) {
    int i = idx + u * stride;
    int row = i / NG, kg = i - row * NG;
    int k8 = kg * 8;
    u16* d = &dst[(long)row * XW + k8];
    if (k8 < 1024) {
      cvt8s(pred + (long)row * D_ + k8, d);
    } else {
      u16x8 z = {};
      *(u16x8*)d = z;
    }
  }
}

// ---------- pre-gather ALL slots' embeddings: EMB[s][b][e] bf16 --------------
__global__ void xgather(const float* __restrict__ emb, const int* __restrict__ labels,
                        u16* __restrict__ EMB) {
  int b = blockIdx.x;
  int e = threadIdx.x;
  #pragma unroll
  for (int s = 0; s < S_; ++s) {
    int ix = labels[s * B_ + b];
    EMB[((long)(s * B_ + b)) * E_ + e] = f2bf(emb[((long)(s * V_ + ix)) * E_ + e]);
  }
}

__global__ void bias_sum(const float* __restrict__ a, const float* __restrict__ b,
                         float* __restrict__ o, int n) {
  int i = blockIdx.x * 256 + threadIdx.x;
  if (i < n) o[i] = a[i] + b[i];
}
__global__ void zero_f(float* __restrict__ p, int n) {
  for (int i = blockIdx.x * 256 + threadIdx.x; i < n; i += gridDim.x * 256) p[i] = 0.f;
}
__global__ void zero_u16k(u16* __restrict__ p, int n) {
  for (int i = blockIdx.x * 256 + threadIdx.x; i < n; i += gridDim.x * 256) p[i] = 0;
}

// ---------------- multi-role deep GEMM (256x256, BK=32, 8 waves) -------------
// Wave tile 128x64 (2M x 4N), acc[8][4]. LDS: A 2-buf + W 3-buf = 80 KiB.
// Per K-tile: {12 ds_read; stage A(t+1) 2 + W(t+2) 2; lgkmcnt(0)+sched_barrier;
// setprio(1); 32 MFMA; setprio(0); vmcnt(2); s_barrier}. Counted vmcnt leaves
// W(t+2) in flight across the barrier (never drained mid-loop). A-rows are
// pair-packed (rows r, r+128 share a 128-B LDS row) so the proven 8-segment
// XOR swizzle (seg ^ row&7) applies: staging writes linear via pre-swizzled
// per-thread (row, col) source; reads XOR the same involution.
// mode 0: LSTM cell epilogue (gate-interleaved W: wave's 64-col span = one
//         interleave group; acc[m][n] = gate n of j=(tn*4+(wave&3))*16+fr).
// mode 1: highway combine (natural rows); mode 2: plain bf16 store.
struct GemmP {
  const u16 *r0, *r1, *r2, *W;
  const float *bsum;
  float *cbuf;
  u16 *hdst;
  float *hf32;
  const u16 *h0src;
  const u16 *xsrc;
  int ld0, ld1, ld2, t1, t2, ldw, nt, ntn, cpx, hld, hoff, h0ld, xld, mode;
};
struct PackP {
  const float *wih0, *whh0, *wih1, *whh1, *hww, *linw;
  u16 *wc0, *wc1, *whn, *wln;
};

__global__ __launch_bounds__(512, 2)
void gemm_multi(GemmP pa, GemmP pb, GemmP pl, GemmP pc, PackP pk,
                int nA, int nAB, int nABL, int nABLC) {
  const int b   = blockIdx.x;
  const int tid = threadIdx.x;

  if (b >= nABLC) {   // ---- pack rider (512 threads, ILP 4) ----
    int rb = b - nABLC;
    if (rb < 208) {
      pk_gates(pk.wih0, pk.whh0, pk.wc0, rb * 512 + tid, 208 * 512,
               208, K0_, 1024, 1536, D0_, H_);
    } else if (rb < 336) {
      pk_gates(pk.wih1, pk.whh1, pk.wc1, (rb - 208) * 512 + tid, 128 * 512,
               128, KX1, 512, 1024, H_, H_);
    } else if (rb < 388) {
      pk_hwn(pk.hww, pk.whn, (rb - 336) * 512 + tid, 52 * 512);
    } else {
      pk_lin(pk.linw, pk.wln, (rb - 388) * 512 + tid, 36 * 512);
    }
    return;
  }

  __shared__ __align__(16) u16 lds[5 * 8192];   // A 2x16KB + W 3x16KB = 80 KiB
  u16* lA = lds;
  u16* lW = lds + 2 * 8192;

  GemmP P = pc; int base = nABL;
  if (b < nABL) { P = pl; base = nAB; }
  if (b < nAB)  { P = pb; base = nA; }
  if (b < nA)   { P = pa; base = 0; }
  const int bidx = b - base;

  const int lane = tid & 63;
  const int wave = tid >> 6;          // 0..7
  const int bid  = (bidx & 7) * P.cpx + (bidx >> 3);   // XCD-chunked (count%8==0)
  const int tn = bid % P.ntn;
  const int tm = bid / P.ntn;
  const long row0 = (long)tm * 256;
  const long col0 = (long)tn * 256;
  const int fr = lane & 15;
  const int ks = lane >> 4;           // 0..3 (K 8-elem group)

  // ---- staging constants: thread -> (logical seg, row, col) -----------------
  const int segL = (tid & 7) ^ ((tid >> 3) & 7);
  const int srow = (tid >> 3) + (segL >> 2) * 128;   // + issue*64
  const int ksg  = (segL & 3) * 8;
  const u16* ga0 = P.r0 + (row0 + srow) * (long)P.ld0 + ksg;
  const u16* ga1 = P.r1 + (row0 + srow) * (long)P.ld1 + ksg;
  const u16* ga2 = P.r2 + (row0 + srow) * (long)P.ld2 + ksg;
  const u16* gww = P.W  + (col0 + srow) * (long)P.ldw + ksg;
  const int dst0 = tid * 8;

  auto stageA = [&](int t, int buf) {   // 2 glds16
    const u16* g; long ld;
    if (t < P.t1)      { g = ga0 + (long)t * 32;          ld = P.ld0; }
    else if (t < P.t2) { g = ga1 + (long)(t - P.t1) * 32; ld = P.ld1; }
    else               { g = ga2 + (long)(t - P.t2) * 32; ld = P.ld2; }
    u16* d = lA + buf * 8192 + dst0;
    glds16(g,               d);
    glds16(g + 64 * ld,     d + 4096);
  };
  auto stageW = [&](int t, int buf) {   // 2 glds16
    const u16* g = gww + (long)t * 32;
    u16* d = lW + buf * 8192 + dst0;
    glds16(g,                       d);
    glds16(g + 64 * (long)P.ldw,    d + 4096);
  };

  // ---- fragment read offsets (u16 units), pair-packed rows ------------------
  const int segA = (wave >> 2) * 4 + ks;          // A half = wave>>2
  const int segW = ((wave & 3) >> 1) * 4 + ks;    // W half = (wn)>>7
  const int wnl  = (wave & 1) * 64;               // W ldsrow base
  int aoff[8], woff[4];
  #pragma unroll
  for (int m = 0; m < 8; ++m)
    aoff[m] = (m * 16 + fr) * 64 + ((segA ^ (fr & 7)) * 8);
  #pragma unroll
  for (int n = 0; n < 4; ++n)
    woff[n] = (wnl + n * 16 + fr) * 64 + ((segW ^ (fr & 7)) * 8);

  f32x4 acc[8][4] = {};
  const int nt = P.nt;

  // ---- prologue: A(0), W(0), W(1); wait A0,W0; barrier ----------------------
  stageA(0, 0);
  stageW(0, 0);
  stageW(1, 1);
  asm volatile("s_waitcnt vmcnt(2)" ::: "memory");
  __builtin_amdgcn_s_barrier();

  int wrd = 0;   // W read buf = t % 3
  for (int t = 0; t < nt; ++t) {
    const u16* Ab = lA + (t & 1) * 8192;
    const u16* Wb = lW + wrd * 8192;
    bf16x8 af[8], wf[4];
    #pragma unroll
    for (int m = 0; m < 8; ++m) af[m] = *(const bf16x8*)&Ab[aoff[m]];
    #pragma unroll
    for (int n = 0; n < 4; ++n) wf[n] = *(const bf16x8*)&Wb[woff[n]];

    if (t + 1 < nt) stageA(t + 1, (t + 1) & 1);
    const int ws2 = (wrd >= 1) ? wrd - 1 : 2;     // (t+2) % 3
    if (t + 2 < nt) stageW(t + 2, ws2);

    asm volatile("s_waitcnt lgkmcnt(0)" ::: "memory");
    __builtin_amdgcn_sched_barrier(0);
    __builtin_amdgcn_s_setprio(1);
    #pragma unroll
    for (int m = 0; m < 8; ++m)
      #pragma unroll
      for (int n = 0; n < 4; ++n)
        acc[m][n] = __builtin_amdgcn_mfma_f32_16x16x32_bf16(af[m], wf[n], acc[m][n], 0, 0, 0);
    __builtin_amdgcn_s_setprio(0);

    if (t + 1 < nt) {
      if (t + 2 < nt) asm volatile("s_waitcnt vmcnt(2)" ::: "memory");
      else            asm volatile("s_waitcnt vmcnt(0)" ::: "memory");
      __builtin_amdgcn_s_barrier();
    }
    wrd = (wrd == 2) ? 0 : wrd + 1;
  }

  const int cr = (lane >> 4) * 4;
  const long rwm = row0 + (wave >> 2) * 128;

  if (P.mode == 0) {
    const int j = (tn * 4 + (wave & 3)) * 16 + fr;
    const float bi = P.bsum[j], bf = P.bsum[512 + j];
    const float bg = P.bsum[1024 + j], bo = P.bsum[1536 + j];
    #pragma unroll
    for (int m = 0; m < 8; ++m) {
      const long rbase = rwm + m * 16 + cr;
      #pragma unroll
      for (int r = 0; r < 4; ++r) {
        const long ri = rbase + r;
        float gi = acc[m][0][r] + bi;
        float gf = acc[m][1][r] + bf;
        float gg = acc[m][2][r] + bg;
        float go = acc[m][3][r] + bo;
        float cv = P.cbuf[ri * H_ + j];
        float cn = sigmoidf_(gf) * cv + sigmoidf_(gi) * tanhf_(gg);
        float hn = sigmoidf_(go) * tanhf_(cn);
        P.cbuf[ri * H_ + j] = cn;
        P.hdst[ri * P.hld + P.hoff + j] = f2bf(hn);
        if (P.hf32) P.hf32[ri * H_ + j] = hn;
      }
    }
  } else if (P.mode == 1) {
    #pragma unroll
    for (int n = 0; n < 4; ++n) {
      const int j = (int)col0 + (wave & 3) * 64 + n * 16 + fr;   // 0..511
      const float bj = P.bsum[j];
      #pragma unroll
      for (int m = 0; m < 8; ++m) {
        const long rbase = rwm + m * 16 + cr;
        #pragma unroll
        for (int r = 0; r < 4; ++r) {
          const long ri = rbase + r;
          float gv = sigmoidf_(acc[m][n][r] + bj);
          float h0 = bf2f(P.h0src[ri * (long)P.h0ld + j]);
          float xl = bf2f(P.xsrc[ri * (long)P.xld + j]);
          float x1 = gv * h0 + (1.f - gv) * xl;
          P.hdst[ri * P.hld + P.hoff + j] = f2bf(x1);
        }
      }
    }
  } else {   // mode 2: plain bf16 store
    #pragma unroll
    for (int n = 0; n < 4; ++n) {
      const int j = (int)col0 + (wave & 3) * 64 + n * 16 + fr;
      #pragma unroll
      for (int m = 0; m < 8; ++m) {
        const long rbase = rwm + m * 16 + cr;
        #pragma unroll
        for (int r = 0; r < 4; ++r)
          P.hdst[(rbase + r) * P.hld + P.hoff + j] = f2bf(acc[m][n][r]);
      }
    }
  }
}

extern "C" void kernel_launch(void* const* d_in, const int* in_sizes, int n_in,
                              void* d_out, int out_size, void* d_ws, size_t ws_size,
                              hipStream_t stream) {
  const float* pred   = (const float*)d_in[0];
  const int*   labels = (const int*)d_in[1];
  const float* emb    = (const float*)d_in[2];
  const float* Wih0   = (const float*)d_in[3];
  const float* Whh0   = (const float*)d_in[4];
  const float* bih0   = (const float*)d_in[5];
  const float* bhh0   = (const float*)d_in[6];
  const float* hwW0   = (const float*)d_in[7];
  const float* hwb0   = (const float*)d_in[8];
  const float* linW0  = (const float*)d_in[9];
  const float* Wih1   = (const float*)d_in[10];
  const float* Whh1   = (const float*)d_in[11];
  const float* bih1   = (const float*)d_in[12];
  const float* bhh1   = (const float*)d_in[13];
  float* out = (float*)d_out;

  char* ws = (char*)d_ws;
  size_t off = 0;
  auto alloc = [&](size_t bytes) {
    char* p = ws + off;
    off = (off + bytes + 255) & ~(size_t)255;
    return p;
  };
  u16* WC0  = (u16*)alloc((size_t)S_ * G4H * K0_ * 2);   // gate-ilv [Wp|Wh|We]
  u16* WC1  = (u16*)alloc((size_t)S_ * G4H * KX1 * 2);   // gate-ilv [Wih1|Whh1]
  u16* HWn  = (u16*)alloc((size_t)S_ * H_ * K0_ * 2);    // hw natural rows
  u16* LNw  = (u16*)alloc((size_t)S_ * H_ * KL_ * 2);    // lin natural rows
  u16* xcat = (u16*)alloc((size_t)B_ * XW * 2);          // [pred|h0_a|h0_b]
  u16* EMB  = (u16*)alloc((size_t)S_ * B_ * E_ * 2);     // pre-gathered embeddings
  u16* x1cat= (u16*)alloc((size_t)B_ * X1W * 2);         // [x1_a|x1_b|h1_a|h1_b]
  u16* xlin = (u16*)alloc((size_t)2 * B_ * H_ * 2);      // lin out, parity dbuf
  float* c0  = (float*)alloc((size_t)B_ * H_ * 4);
  float* c1  = (float*)alloc((size_t)B_ * H_ * 4);
  float* bs0 = (float*)alloc((size_t)S_ * G4H * 4);
  float* bs1 = (float*)alloc((size_t)S_ * G4H * 4);

  auto mkPk = [&](int s) {
    PackP K;
    K.wih0 = Wih0 + (size_t)s * G4H * D0_;
    K.whh0 = Whh0 + (size_t)s * G4H * H_;
    K.wih1 = Wih1 + (size_t)s * G4H * H_;
    K.whh1 = Whh1 + (size_t)s * G4H * H_;
    K.hww  = hwW0 + (size_t)s * H_ * K0_;
    K.linw = linW0 + (size_t)s * H_ * KL_;
    K.wc0  = WC0 + (size_t)s * G4H * K0_;
    K.wc1  = WC1 + (size_t)s * G4H * KX1;
    K.whn  = HWn + (size_t)s * H_ * K0_;
    K.wln  = LNw + (size_t)s * H_ * KL_;
    return K;
  };

  // -------- phase A: slot-0 pack (rider-only launch) + state init -------------
  GemmP z = {};
  gemm_multi<<<424, 512, 0, stream>>>(z, z, z, z, mkPk(0), 0, 0, 0, 0);
  pack_predz4<<<1024, 256, 0, stream>>>(pred, xcat);
  xgather<<<B_, E_, 0, stream>>>(emb, labels, EMB);
  bias_sum<<<56, 256, 0, stream>>>(bih0, bhh0, bs0, S_ * G4H);
  bias_sum<<<56, 256, 0, stream>>>(bih1, bhh1, bs1, S_ * G4H);
  zero_f<<<256, 256, 0, stream>>>(c0, B_ * H_);
  zero_f<<<256, 256, 0, stream>>>(c1, B_ * H_);
  zero_u16k<<<2048, 256, 0, stream>>>(x1cat, B_ * X1W);

  // -------- role builders (256x256 tile, BK=32) -------------------------------
  auto mkA = [&](int s) {              // G0_s: [pred|h0_{s-1}|emb_s] @ WC0_s^T
    GemmP P = {};
    P.r0 = xcat;                               P.ld0 = XW;  P.t1 = 32;
    P.r1 = xcat + 1024 + ((s + 1) & 1) * 512;  P.ld1 = XW;  P.t2 = 48;
    P.r2 = EMB + (size_t)s * B_ * E_;          P.ld2 = E_;
    P.W = WC0 + (size_t)s * G4H * K0_;         P.ldw = K0_; P.nt = 52;
    P.ntn = 8; P.cpx = 16;                     // 128 blocks
    P.bsum = bs0 + (size_t)s * G4H; P.cbuf = c0;
    P.hdst = xcat; P.hld = XW; P.hoff = 1024 + (s & 1) * 512;
    P.hf32 = nullptr; P.h0src = xcat; P.h0ld = 0; P.xsrc = xcat; P.xld = 0;
    P.mode = 0;
    return P;
  };
  auto mkB = [&](int s) {              // HW_s: [pred|h0_s|emb_s] @ hwW_s^T (N=512)
    GemmP P = {};
    P.r0 = xcat;                               P.ld0 = XW;  P.t1 = 32;
    P.r1 = xcat + 1024 + (s & 1) * 512;        P.ld1 = XW;  P.t2 = 48;
    P.r2 = EMB + (size_t)s * B_ * E_;          P.ld2 = E_;
    P.W = HWn + (size_t)s * H_ * K0_;          P.ldw = K0_; P.nt = 52;
    P.ntn = 2; P.cpx = 4;                      // 32 blocks
    P.bsum = hwb0 + (size_t)s * H_; P.cbuf = nullptr;
    P.hdst = x1cat; P.hld = X1W; P.hoff = (s & 1) * 512;
    P.hf32 = nullptr;
    P.h0src = xcat + 1024 + (s & 1) * 512; P.h0ld = XW;
    P.xsrc = xlin + (size_t)(s & 1) * B_ * H_; P.xld = H_;
    P.mode = 1;
    return P;
  };
  auto mkL = [&](int s) {              // LIN_s: [pred|emb_s] @ linW_s^T (N=512)
    GemmP P = {};
    P.r0 = xcat;                               P.ld0 = XW;  P.t1 = 32;
    P.r1 = xcat;                               P.ld1 = XW;  P.t2 = 32;
    P.r2 = EMB + (size_t)s * B_ * E_;          P.ld2 = E_;
    P.W = LNw + (size_t)s * H_ * KL_;          P.ldw = KL_; P.nt = 36;
    P.ntn = 2; P.cpx = 4;                      // 32 blocks
    P.bsum = hwb0; P.cbuf = nullptr;
    P.hdst = xlin + (size_t)(s & 1) * B_ * H_; P.hld = H_; P.hoff = 0;
    P.hf32 = nullptr; P.h0src = xcat; P.h0ld = 0; P.xsrc = xcat; P.xld = 0;
    P.mode = 2;
    return P;
  };
  auto mkC = [&](int s) {              // G1_s: [x1_s|h1_{s-1}] @ WC1_s^T
    GemmP P = {};
    P.r0 = x1cat + (s & 1) * 512;              P.ld0 = X1W; P.t1 = 16;
    P.r1 = x1cat + 1024 + ((s + 1) & 1) * 512; P.ld1 = X1W; P.t2 = 32;
    P.r2 = P.r0;                               P.ld2 = X1W;
    P.W = WC1 + (size_t)s * G4H * KX1;         P.ldw = KX1; P.nt = 32;
    P.ntn = 8; P.cpx = 16;                     // 128 blocks
    P.bsum = bs1 + (size_t)s * G4H; P.cbuf = c1;
    P.hdst = x1cat; P.hld = X1W; P.hoff = 1024 + (s & 1) * 512;
    P.hf32 = (s == 6) ? out : nullptr; P.h0src = x1cat; P.h0ld = 0;
    P.xsrc = x1cat; P.xld = 0;
    P.mode = 0;
    return P;
  };

  // ---- pipelined slot loop: L_k = { G0_k, HW_{k-1}, LIN_k, G1_{k-2}, pack_{k+1} }
  for (int k = 0; k <= 8; ++k) {
    const int nA = (k <= 6) ? 128 : 0;
    const int nB = (k >= 1 && k <= 7) ? 32 : 0;
    const int nL = (k <= 6) ? 32 : 0;
    const int nC = (k >= 2) ? 128 : 0;
    const int nD = (k <= 5) ? 424 : 0;
    GemmP pa, pb, pl, pc;
    if (nA) pa = mkA(k);
    if (nB) pb = mkB(k - 1);
    if (nL) pl = mkL(k);
    if (nC) pc = mkC(k - 2);
    GemmP any = nA ? pa : (nB ? pb : (nL ? pl : pc));
    if (!nA) pa = any;
    if (!nB) pb = any;
    if (!nL) pl = any;
    if (!nC) pc = any;
    PackP pk = mkPk(nD ? (k + 1) : 0);
    gemm_multi<<<nA + nB + nL + nC + nD, 512, 0, stream>>>(
        pa, pb, pl, pc, pk, nA, nA + nB, nA + nB + nL, nA + nB + nL + nC);
  }
}

// Round 15
// 620.672 us; speedup vs baseline: 1.4573x; 1.4573x over previous
//
#include <hip/hip_runtime.h>
#include <stdint.h>

typedef unsigned short u16;

#define S_   7
#define B_   4096
#define D_   1024
#define E_   128
#define H_   512
#define V_   200
#define D0_  1152   // D+E
#define K0_  1664   // layer-0 GEMM K: pred 1024 + h0 512 + emb 128
#define KL_  1152   // lin GEMM K: pred 1024 + emb 128
#define KX1  1024   // layer-1 GEMM K: x1 512 + h1 512
#define G4H  2048   // 4H
#define XW   2048   // xcat width: [pred(1024) | h0_a(512) | h0_b(512)]
#define X1W  2048   // x1cat width: [x1_a | x1_b | h1_a | h1_b]

typedef __bf16 bf16x8 __attribute__((ext_vector_type(8)));
typedef float  f32x4  __attribute__((ext_vector_type(4)));
typedef u16    u16x8  __attribute__((ext_vector_type(8)));

__device__ __forceinline__ u16 f2bf(float f) {
  union { float f; uint32_t u; } v; v.f = f;
  uint32_t r = v.u + 0x7fffu + ((v.u >> 16) & 1u);   // RNE
  return (u16)(r >> 16);
}
__device__ __forceinline__ float bf2f(u16 b) {
  union { uint32_t u; float f; } v; v.u = ((uint32_t)b) << 16;
  return v.f;
}
__device__ __forceinline__ float sigmoidf_(float x) { return 1.0f / (1.0f + __expf(-x)); }
__device__ __forceinline__ float tanhf_(float x) {
  float t = __expf(-2.f * fabsf(x));
  return copysignf((1.f - t) / (1.f + t), x);
}

__device__ __forceinline__ void glds16(const u16* g, u16* l) {
  __builtin_amdgcn_global_load_lds(
      (const __attribute__((address_space(1))) uint32_t*)g,
      (__attribute__((address_space(3))) uint32_t*)l, 16, 0, 0);
}

__device__ __forceinline__ void cvt8s(const float* src, u16* dst) {
  const float4* p = (const float4*)src;
  float4 x = p[0], y = p[1];
  u16x8 o;
  o[0]=f2bf(x.x); o[1]=f2bf(x.y); o[2]=f2bf(x.z); o[3]=f2bf(x.w);
  o[4]=f2bf(y.x); o[5]=f2bf(y.y); o[6]=f2bf(y.z); o[7]=f2bf(y.w);
  *(u16x8*)dst = o;
}

// ---------- pack device fns (per-slot pointers) ------------------------------
__device__ __forceinline__ void pk_gates(const float* __restrict__ Wih,
                                         const float* __restrict__ Whh,
                                         u16* __restrict__ dst,
                                         int idx, int stride, int NG, int KK,
                                         int P1, int P2, int KA, int KB) {
  #pragma unroll
  for (int u = 0; u < 4; ++u) {
    int i = idx + u * stride;
    int r = i / NG, kg = i - r * NG;
    int k8 = kg * 8;
    int g = r >> 9, j = r & 511;
    long drow = (j >> 4) * 64 + g * 16 + (j & 15);
    const float* sp = (k8 < P1) ? Wih + (long)r * KA + k8
                    : (k8 < P2) ? Whh + (long)r * KB + (k8 - P1)
                                : Wih + (long)r * KA + P1 + (k8 - P2);
    cvt8s(sp, &dst[drow * KK + k8]);
  }
}
__device__ __forceinline__ void pk_hwn(const float* __restrict__ src,
                                       u16* __restrict__ dst,
                                       int idx, int stride) {
  #pragma unroll
  for (int u = 0; u < 4; ++u) {
    int i = idx + u * stride;
    int r = i / 208, kg = i - r * 208;
    int k8 = kg * 8;
    const float* sp = (k8 < 1024) ? src + (long)r * K0_ + k8
                    : (k8 < 1536) ? src + (long)r * K0_ + 1152 + (k8 - 1024)
                                  : src + (long)r * K0_ + 1024 + (k8 - 1536);
    cvt8s(sp, &dst[(long)r * K0_ + k8]);
  }
}
__device__ __forceinline__ void pk_lin(const float* __restrict__ src,
                                       u16* __restrict__ dst,
                                       int idx, int stride) {
  #pragma unroll
  for (int u = 0; u < 4; ++u) {
    int i = idx + u * stride;
    int r = i / 144, kg = i - r * 144;
    int k8 = kg * 8;
    cvt8s(src + (long)r * KL_ + k8, &dst[(long)r * KL_ + k8]);
  }
}

// ---------------- multi-role fused GEMM + pack/init riders -------------------
// Engine = round-8 config (best measured, ~660 TF): 128x128 tile, BK=64, A+W
// via global_load_lds into double-buffered LDS (64 KiB), prefetch-(t+1)-then-
// compute-t, syncthreads pacing, XOR-swizzled staging, XCD-chunked remap,
// 4 waves (2x2 of 64x64), 16x16x32 MFMA.
// Roles per launch: A=G0_k, B=HW_{k-1}, L=LIN_k, C=G1_{k-2} (block-range
// select). Riders: [nABLC, nABLC+nPk) pack slot weights; blocks beyond (phase
// A only) run the init work (pred pack, emb gather, bias sums, h1_b zero).
// mode 0: LSTM cell epilogue (gate-interleaved W; acc[m][0..3] = i,f,g,o;
//         czero=1 substitutes c=0 for the first slot).
// mode 1: highway combine (natural-row W; reads h0 + xlin, writes x1).
// mode 2: plain bf16 store (LIN -> xlin buffer).
struct GemmP {
  const u16 *r0, *r1, *r2, *W;
  const float *bsum;
  float *cbuf;
  u16 *hdst;
  float *hf32;
  const u16 *h0src;
  const u16 *xsrc;
  int ld0, ld1, ld2, t1, t2, ldw, nt, ntn, cpx, hld, hoff, h0ld, xld, mode, czero;
};
struct PackP {
  const float *wih0, *whh0, *wih1, *whh1, *hww, *linw;
  u16 *wc0, *wc1, *whn, *wln;
};
struct InitP {
  const float *pred;
  const int   *labels;
  const float *emb;
  const float *bih0, *bhh0, *bih1, *bhh1;
  u16 *xcat, *EMB, *h1z;     // h1z = x1cat + 1536 (h1_b region)
  float *bs0, *bs1;
};

__global__ __launch_bounds__(256)
void gemm_multi(GemmP pa, GemmP pb, GemmP pl, GemmP pc, PackP pk, InitP ini,
                int nA, int nAB, int nABL, int nABLC, int nPk) {
  const int b   = blockIdx.x;
  const int tid = threadIdx.x;

  if (b >= nABLC) {   // ---- rider blocks ----
    int rb = b - nABLC;
    if (rb < nPk) {   // weight packs for one slot (848 blocks, ILP 4)
      if (rb < 416) {
        pk_gates(pk.wih0, pk.whh0, pk.wc0, rb * 256 + tid, 416 * 256,
                 208, K0_, 1024, 1536, D0_, H_);
      } else if (rb < 672) {
        pk_gates(pk.wih1, pk.whh1, pk.wc1, (rb - 416) * 256 + tid, 256 * 256,
                 128, KX1, 512, 1024, H_, H_);
      } else if (rb < 776) {
        pk_hwn(pk.hww, pk.whn, (rb - 672) * 256 + tid, 104 * 256);
      } else {
        pk_lin(pk.linw, pk.wln, (rb - 776) * 256 + tid, 72 * 256);
      }
      return;
    }
    // ---- phase-A init riders ----
    int ib = rb - nPk;
    if (ib < 1024) {              // pred -> xcat[:,0..1024), zero h0 slots
      int idx = ib * 256 + tid;
      #pragma unroll
      for (int u = 0; u < 4; ++u) {
        int i = idx + u * (1024 * 256);
        int row = i >> 8, kg = i & 255;     // NG = XW/8 = 256
        int k8 = kg * 8;
        u16* d = &ini.xcat[(long)row * XW + k8];
        if (k8 < 1024) {
          cvt8s(ini.pred + (long)row * D_ + k8, d);
        } else {
          u16x8 z = {};
          *(u16x8*)d = z;
        }
      }
    } else if (ib < 3072) {       // embedding gather for all slots
      int bb = (ib - 1024) * 2 + (tid >> 7);
      int e = tid & 127;
      #pragma unroll
      for (int s = 0; s < S_; ++s) {
        int ix = ini.labels[s * B_ + bb];
        ini.EMB[((long)(s * B_ + bb)) * E_ + e] =
            f2bf(ini.emb[((long)(s * V_ + ix)) * E_ + e]);
      }
    } else if (ib < 3184) {       // bias sums (112 blocks = 2 x 14336 elems)
      int i = (ib - 3072) * 256 + tid;
      if (i < S_ * G4H) ini.bs0[i] = ini.bih0[i] + ini.bhh0[i];
      else { int j = i - S_ * G4H; ini.bs1[j] = ini.bih1[j] + ini.bhh1[j]; }
    } else {                      // zero h1_b region (512 blocks, 2 stores/thr)
      int idx = (ib - 3184) * 256 + tid;
      u16x8 z = {};
      #pragma unroll
      for (int u = 0; u < 2; ++u) {
        int f = idx + u * (512 * 256);
        int row = f >> 6, c8 = f & 63;      // 512 cols / 8 = 64 chunks per row
        *(u16x8*)&ini.h1z[(long)row * X1W + c8 * 8] = z;
      }
    }
    return;
  }

  __shared__ __align__(16) u16 lds[4 * 8192];   // A buf0/1, W buf0/1 -> 64 KiB
  GemmP P = pc; int base = nABL;
  if (b < nABL) { P = pl; base = nAB; }
  if (b < nAB)  { P = pb; base = nA; }
  if (b < nA)   { P = pa; base = 0; }
  const int bidx = b - base;

  u16* lA = lds;
  u16* lW = lds + 2 * 8192;
  const int lane = tid & 63;
  const int wave = tid >> 6;
  const int bid  = (bidx & 7) * P.cpx + (bidx >> 3);   // XCD-chunked (count%8==0)
  const int tn = bid % P.ntn;
  const int tm = bid / P.ntn;
  const long row0 = (long)tm * 128;
  const long col0 = (long)tn * 128;
  const int wm = (wave >> 1) * 64;
  const int wn = (wave & 1) * 64;
  const int fr = lane & 15;
  const int fk = (lane >> 4) * 8;
  const int wr = wave * 32;

  const int srow = wr + (lane >> 3);
  const int scol = ((lane & 7) ^ ((lane >> 3) & 7)) * 8;
  const u16* gr0 = P.r0 + (row0 + srow) * (long)P.ld0 + scol;
  const u16* gr1 = P.r1 + (row0 + srow) * (long)P.ld1 + scol;
  const u16* gr2 = P.r2 + (row0 + srow) * (long)P.ld2 + scol;
  const u16* gw  = P.W  + (col0 + srow) * (long)P.ldw + scol;
  const int dst0 = wr * 64 + lane * 8;

  auto stage = [&](int t, int buf) {
    const u16* g; long ld;
    if (t < P.t1)      { g = gr0 + (long)t * 64;          ld = P.ld0; }
    else if (t < P.t2) { g = gr1 + (long)(t - P.t1) * 64; ld = P.ld1; }
    else               { g = gr2 + (long)(t - P.t2) * 64; ld = P.ld2; }
    const u16* gww = gw + (long)t * 64;
    u16* dA = lA + buf * 8192 + dst0;
    u16* dW = lW + buf * 8192 + dst0;
    #pragma unroll
    for (int i = 0; i < 4; ++i) {
      glds16(g   + (long)(i * 8) * ld,    dA + i * 512);
      glds16(gww + (long)(i * 8) * P.ldw, dW + i * 512);
    }
  };

  int aoff[4], woff[4];
  #pragma unroll
  for (int m = 0; m < 4; ++m) aoff[m] = (wm + m * 16 + fr) * 64;
  #pragma unroll
  for (int n = 0; n < 4; ++n) woff[n] = (wn + n * 16 + fr) * 64;
  const int swz = (fr & 7) << 3;
  const int kk0 = (0 + fk) ^ swz;
  const int kk1 = (32 + fk) ^ swz;

  f32x4 acc[4][4] = {};
  const int nt = P.nt;

  stage(0, 0);

  for (int t = 0; t < nt; ++t) {
    __syncthreads();                  // tile t DMA complete in buf (t&1)
    if (t + 1 < nt) stage(t + 1, (t + 1) & 1);
    const u16* Ab = lA + (t & 1) * 8192;
    const u16* Wb = lW + (t & 1) * 8192;
    bf16x8 af0[4], wf0[4], af1[4], wf1[4];
    #pragma unroll
    for (int m = 0; m < 4; ++m) af0[m] = *(const bf16x8*)&Ab[aoff[m] + kk0];
    #pragma unroll
    for (int n = 0; n < 4; ++n) wf0[n] = *(const bf16x8*)&Wb[woff[n] + kk0];
    #pragma unroll
    for (int m = 0; m < 4; ++m) af1[m] = *(const bf16x8*)&Ab[aoff[m] + kk1];
    #pragma unroll
    for (int n = 0; n < 4; ++n) wf1[n] = *(const bf16x8*)&Wb[woff[n] + kk1];
    #pragma unroll
    for (int m = 0; m < 4; ++m)
      #pragma unroll
      for (int n = 0; n < 4; ++n)
        acc[m][n] = __builtin_amdgcn_mfma_f32_16x16x32_bf16(af0[m], wf0[n], acc[m][n], 0, 0, 0);
    #pragma unroll
    for (int m = 0; m < 4; ++m)
      #pragma unroll
      for (int n = 0; n < 4; ++n)
        acc[m][n] = __builtin_amdgcn_mfma_f32_16x16x32_bf16(af1[m], wf1[n], acc[m][n], 0, 0, 0);
  }

  const int cr = (lane >> 4) * 4;
  const int jg = wn >> 6;   // 0 or 1

  if (P.mode == 0) {
    const int j = tn * 32 + jg * 16 + fr;
    const float bi = P.bsum[j], bf = P.bsum[512 + j];
    const float bg = P.bsum[1024 + j], bo = P.bsum[1536 + j];
    #pragma unroll
    for (int m = 0; m < 4; ++m) {
      const long rbase = row0 + wm + m * 16 + cr;
      #pragma unroll
      for (int r = 0; r < 4; ++r) {
        const long ri = rbase + r;
        float gi = acc[m][0][r] + bi;
        float gf = acc[m][1][r] + bf;
        float gg = acc[m][2][r] + bg;
        float go = acc[m][3][r] + bo;
        float cv = P.czero ? 0.f : P.cbuf[ri * H_ + j];
        float cn = sigmoidf_(gf) * cv + sigmoidf_(gi) * tanhf_(gg);
        float hn = sigmoidf_(go) * tanhf_(cn);
        P.cbuf[ri * H_ + j] = cn;
        P.hdst[ri * P.hld + P.hoff + j] = f2bf(hn);
        if (P.hf32) P.hf32[ri * H_ + j] = hn;
      }
    }
  } else if (P.mode == 1) {
    #pragma unroll
    for (int n = 0; n < 4; ++n) {
      const int j = (int)(col0) + wn + n * 16 + fr;   // 0..511 (N=512)
      const float bj = P.bsum[j];
      #pragma unroll
      for (int m = 0; m < 4; ++m) {
        const long rbase = row0 + wm + m * 16 + cr;
        #pragma unroll
        for (int r = 0; r < 4; ++r) {
          const long ri = rbase + r;
          float gv = sigmoidf_(acc[m][n][r] + bj);
          float h0 = bf2f(P.h0src[ri * (long)P.h0ld + j]);
          float xl = bf2f(P.xsrc[ri * (long)P.xld + j]);
          float x1 = gv * h0 + (1.f - gv) * xl;
          P.hdst[ri * P.hld + P.hoff + j] = f2bf(x1);
        }
      }
    }
  } else {   // mode 2: plain bf16 store
    #pragma unroll
    for (int n = 0; n < 4; ++n) {
      const int j = (int)(col0) + wn + n * 16 + fr;
      #pragma unroll
      for (int m = 0; m < 4; ++m) {
        const long rbase = row0 + wm + m * 16 + cr;
        #pragma unroll
        for (int r = 0; r < 4; ++r)
          P.hdst[(rbase + r) * P.hld + P.hoff + j] = f2bf(acc[m][n][r]);
      }
    }
  }
}

extern "C" void kernel_launch(void* const* d_in, const int* in_sizes, int n_in,
                              void* d_out, int out_size, void* d_ws, size_t ws_size,
                              hipStream_t stream) {
  const float* pred   = (const float*)d_in[0];
  const int*   labels = (const int*)d_in[1];
  const float* emb    = (const float*)d_in[2];
  const float* Wih0   = (const float*)d_in[3];
  const float* Whh0   = (const float*)d_in[4];
  const float* bih0   = (const float*)d_in[5];
  const float* bhh0   = (const float*)d_in[6];
  const float* hwW0   = (const float*)d_in[7];
  const float* hwb0   = (const float*)d_in[8];
  const float* linW0  = (const float*)d_in[9];
  const float* Wih1   = (const float*)d_in[10];
  const float* Whh1   = (const float*)d_in[11];
  const float* bih1   = (const float*)d_in[12];
  const float* bhh1   = (const float*)d_in[13];
  float* out = (float*)d_out;

  char* ws = (char*)d_ws;
  size_t off = 0;
  auto alloc = [&](size_t bytes) {
    char* p = ws + off;
    off = (off + bytes + 255) & ~(size_t)255;
    return p;
  };
  u16* WC0  = (u16*)alloc((size_t)S_ * G4H * K0_ * 2);   // gate-ilv [Wp|Wh|We]
  u16* WC1  = (u16*)alloc((size_t)S_ * G4H * KX1 * 2);   // gate-ilv [Wih1|Whh1]
  u16* HWn  = (u16*)alloc((size_t)S_ * H_ * K0_ * 2);    // hw natural rows
  u16* LNw  = (u16*)alloc((size_t)S_ * H_ * KL_ * 2);    // lin natural rows
  u16* xcat = (u16*)alloc((size_t)B_ * XW * 2);          // [pred|h0_a|h0_b]
  u16* EMB  = (u16*)alloc((size_t)S_ * B_ * E_ * 2);     // pre-gathered embeddings
  u16* x1cat= (u16*)alloc((size_t)B_ * X1W * 2);         // [x1_a|x1_b|h1_a|h1_b]
  u16* xlin = (u16*)alloc((size_t)2 * B_ * H_ * 2);      // lin out, parity dbuf
  float* c0  = (float*)alloc((size_t)B_ * H_ * 4);
  float* c1  = (float*)alloc((size_t)B_ * H_ * 4);
  float* bs0 = (float*)alloc((size_t)S_ * G4H * 4);
  float* bs1 = (float*)alloc((size_t)S_ * G4H * 4);

  auto mkPk = [&](int s) {
    PackP K;
    K.wih0 = Wih0 + (size_t)s * G4H * D0_;
    K.whh0 = Whh0 + (size_t)s * G4H * H_;
    K.wih1 = Wih1 + (size_t)s * G4H * H_;
    K.whh1 = Whh1 + (size_t)s * G4H * H_;
    K.hww  = hwW0 + (size_t)s * H_ * K0_;
    K.linw = linW0 + (size_t)s * H_ * KL_;
    K.wc0  = WC0 + (size_t)s * G4H * K0_;
    K.wc1  = WC1 + (size_t)s * G4H * KX1;
    K.whn  = HWn + (size_t)s * H_ * K0_;
    K.wln  = LNw + (size_t)s * H_ * KL_;
    return K;
  };

  // -------- phase A: ONE launch = slot-0 packs + all init riders --------------
  GemmP z = {};
  InitP ini;
  ini.pred = pred; ini.labels = labels; ini.emb = emb;
  ini.bih0 = bih0; ini.bhh0 = bhh0; ini.bih1 = bih1; ini.bhh1 = bhh1;
  ini.xcat = xcat; ini.EMB = EMB; ini.h1z = x1cat + 1536;
  ini.bs0 = bs0; ini.bs1 = bs1;
  // grid = 848 packs + 1024 pred + 2048 gather + 112 bias + 512 zero = 4544
  gemm_multi<<<4544, 256, 0, stream>>>(z, z, z, z, mkPk(0), ini, 0, 0, 0, 0, 848);

  InitP iniz = {};

  // -------- role builders (128x128 tile engine) -------------------------------
  auto mkA = [&](int s) {              // G0_s: [pred|h0_{s-1}|emb_s] @ WC0_s^T
    GemmP P = {};
    P.r0 = xcat;                               P.ld0 = XW;  P.t1 = 16;
    P.r1 = xcat + 1024 + ((s + 1) & 1) * 512;  P.ld1 = XW;  P.t2 = 24;
    P.r2 = EMB + (size_t)s * B_ * E_;          P.ld2 = E_;
    P.W = WC0 + (size_t)s * G4H * K0_;         P.ldw = K0_; P.nt = 26;
    P.ntn = 16; P.cpx = 64;                    // 512 blocks
    P.bsum = bs0 + (size_t)s * G4H; P.cbuf = c0;
    P.hdst = xcat; P.hld = XW; P.hoff = 1024 + (s & 1) * 512;
    P.hf32 = nullptr; P.h0src = xcat; P.h0ld = 0; P.xsrc = xcat; P.xld = 0;
    P.mode = 0; P.czero = (s == 0);
    return P;
  };
  auto mkB = [&](int s) {              // HW_s: [pred|h0_s|emb_s] @ hwW_s^T (N=512)
    GemmP P = {};
    P.r0 = xcat;                               P.ld0 = XW;  P.t1 = 16;
    P.r1 = xcat + 1024 + (s & 1) * 512;        P.ld1 = XW;  P.t2 = 24;
    P.r2 = EMB + (size_t)s * B_ * E_;          P.ld2 = E_;
    P.W = HWn + (size_t)s * H_ * K0_;          P.ldw = K0_; P.nt = 26;
    P.ntn = 4; P.cpx = 16;                     // 128 blocks
    P.bsum = hwb0 + (size_t)s * H_; P.cbuf = nullptr;
    P.hdst = x1cat; P.hld = X1W; P.hoff = (s & 1) * 512;
    P.hf32 = nullptr;
    P.h0src = xcat + 1024 + (s & 1) * 512; P.h0ld = XW;
    P.xsrc = xlin + (size_t)(s & 1) * B_ * H_; P.xld = H_;
    P.mode = 1; P.czero = 0;
    return P;
  };
  auto mkL = [&](int s) {              // LIN_s: [pred|emb_s] @ linW_s^T (N=512)
    GemmP P = {};
    P.r0 = xcat;                               P.ld0 = XW;  P.t1 = 16;
    P.r1 = xcat;                               P.ld1 = XW;  P.t2 = 16;
    P.r2 = EMB + (size_t)s * B_ * E_;          P.ld2 = E_;
    P.W = LNw + (size_t)s * H_ * KL_;          P.ldw = KL_; P.nt = 18;
    P.ntn = 4; P.cpx = 16;                     // 128 blocks
    P.bsum = hwb0; P.cbuf = nullptr;
    P.hdst = xlin + (size_t)(s & 1) * B_ * H_; P.hld = H_; P.hoff = 0;
    P.hf32 = nullptr; P.h0src = xcat; P.h0ld = 0; P.xsrc = xcat; P.xld = 0;
    P.mode = 2; P.czero = 0;
    return P;
  };
  auto mkC = [&](int s) {              // G1_s: [x1_s|h1_{s-1}] @ WC1_s^T
    GemmP P = {};
    P.r0 = x1cat + (s & 1) * 512;              P.ld0 = X1W; P.t1 = 8;
    P.r1 = x1cat + 1024 + ((s + 1) & 1) * 512; P.ld1 = X1W; P.t2 = 16;
    P.r2 = P.r0;                               P.ld2 = X1W;
    P.W = WC1 + (size_t)s * G4H * KX1;         P.ldw = KX1; P.nt = 16;
    P.ntn = 16; P.cpx = 64;                    // 512 blocks
    P.bsum = bs1 + (size_t)s * G4H; P.cbuf = c1;
    P.hdst = x1cat; P.hld = X1W; P.hoff = 1024 + (s & 1) * 512;
    P.hf32 = (s == 6) ? out : nullptr; P.h0src = x1cat; P.h0ld = 0;
    P.xsrc = x1cat; P.xld = 0;
    P.mode = 0; P.czero = (s == 0);
    return P;
  };

  // ---- pipelined slot loop: L_k = { G0_k, HW_{k-1}, LIN_k, G1_{k-2}, pack_{k+1} }
  for (int k = 0; k <= 8; ++k) {
    const int nA = (k <= 6) ? 512 : 0;
    const int nB = (k >= 1 && k <= 7) ? 128 : 0;
    const int nL = (k <= 6) ? 128 : 0;
    const int nC = (k >= 2) ? 512 : 0;
    const int nD = (k <= 5) ? 848 : 0;
    GemmP pa, pb, pl, pc;
    if (nA) pa = mkA(k);
    if (nB) pb = mkB(k - 1);
    if (nL) pl = mkL(k);
    if (nC) pc = mkC(k - 2);
    GemmP any = nA ? pa : (nB ? pb : (nL ? pl : pc));
    if (!nA) pa = any;
    if (!nB) pb = any;
    if (!nL) pl = any;
    if (!nC) pc = any;
    PackP pk = mkPk(nD ? (k + 1) : 0);
    gemm_multi<<<nA + nB + nL + nC + nD, 256, 0, stream>>>(
        pa, pb, pl, pc, pk, iniz, nA, nA + nB, nA + nB + nL, nA + nB + nL + nC, 848);
  }
}